// Round 3
// baseline (420.553 us; speedup 1.0000x reference)
//
#include <hip/hip_runtime.h>
#include <hip/hip_bf16.h>
#include <stdint.h>

typedef __attribute__((ext_vector_type(8))) unsigned short ushort8v;

__device__ __forceinline__ float bf2f(unsigned short u) {
    return __uint_as_float(((unsigned)u) << 16);
}
__device__ __forceinline__ unsigned short f2bf(float f) {
    unsigned u = __float_as_uint(f);
    unsigned r = u + 0x7fffu + ((u >> 16) & 1u);   // round-to-nearest-even
    return (unsigned short)(r >> 16);
}

// Pre-pass: planes (3 x [C=32][H=256][W=256] f32) -> ws [3][y][x][c=32] bf16.
__global__ __launch_bounds__(256) void transpose_planes_kernel(
    const float* __restrict__ pxy,
    const float* __restrict__ pxz,
    const float* __restrict__ pyz,
    unsigned int* __restrict__ tp)   // [3*256*256*16] u32 (bf16 pairs, channel-fastest)
{
    int t = blockIdx.x * 256 + threadIdx.x;
    if (t >= 3 * 256 * 256 * 16) return;
    int cp  = t & 15;           // channel pair 0..15
    int tex = t >> 4;           // p*65536 + y*256 + x
    int p   = tex >> 16;
    int yx  = tex & 65535;
    const float* src = (p == 0) ? pxy : ((p == 1) ? pxz : pyz);
    float f0 = src[(size_t)(2 * cp)     * 65536 + yx];
    float f1 = src[(size_t)(2 * cp + 1) * 65536 + yx];
    tp[t] = ((unsigned)f2bf(f1) << 16) | (unsigned)f2bf(f0);
}

template<bool TP>
__global__ __launch_bounds__(256) void nerf_fused_kernel(
    const float* __restrict__ xin,
    const float* __restrict__ pxy,
    const float* __restrict__ pxz,
    const float* __restrict__ pyz,
    const unsigned short* __restrict__ tp,   // transposed bf16 planes (if TP)
    const float* __restrict__ center,
    const float* __restrict__ scale,
    const float* __restrict__ w1,    // (96,64)
    const float* __restrict__ w2,    // (64,16)
    const float* __restrict__ wc1,   // (15,64)
    const float* __restrict__ wc2,   // (64,64)
    const float* __restrict__ wc3,   // (64,3)
    float* __restrict__ out,         // f32: color (N,3) then sigma (N)
    int npts)
{
    // Per-thread activation stash; column = own tid, so NO barriers needed.
    __shared__ unsigned short act[64][256];
    const int tid = threadIdx.x;
    const int i = blockIdx.x * 256 + tid;
    if (i >= npts) return;

    const float xv = xin[3 * i + 0];
    const float yv = xin[3 * i + 1];
    const float zv = xin[3 * i + 2];

    auto norm1 = [&](float v, int k) {
        float xn = fminf(fmaxf((v - center[k]) / scale[k] + 0.5f, 0.0f), 1.0f);
        return xn * 2.0f - 1.0f;
    };
    const float gx = norm1(xv, 0);
    const float gy = norm1(yv, 1);
    const float gz = norm1(zv, 2);

    float h[64];
    #pragma unroll
    for (int j = 0; j < 64; ++j) h[j] = 0.0f;

    // Bilinear sample one plane (32 ch) and accumulate layer-1 on the fly.
    auto samp = [&](float gu, float gv, int pl, const float* __restrict__ splane) {
        float pxf = (gu + 1.0f) * 0.5f * 255.0f;
        float pyf = (gv + 1.0f) * 0.5f * 255.0f;
        float x0f = floorf(pxf), y0f = floorf(pyf);
        float wx = pxf - x0f, wy = pyf - y0f;
        int x0 = (int)x0f, y0 = (int)y0f;
        x0 = min(max(x0, 0), 255);
        y0 = min(max(y0, 0), 255);
        int x1 = min(x0 + 1, 255), y1 = min(y0 + 1, 255);
        float w00 = (1.0f - wx) * (1.0f - wy), w01 = wx * (1.0f - wy);
        float w10 = (1.0f - wx) * wy,          w11 = wx * wy;
        if constexpr (TP) {
            const ushort8v* r00 = (const ushort8v*)(tp + (((size_t)pl << 16) + (size_t)(y0 * 256 + x0)) * 32);
            const ushort8v* r01 = (const ushort8v*)(tp + (((size_t)pl << 16) + (size_t)(y0 * 256 + x1)) * 32);
            const ushort8v* r10 = (const ushort8v*)(tp + (((size_t)pl << 16) + (size_t)(y1 * 256 + x0)) * 32);
            const ushort8v* r11 = (const ushort8v*)(tp + (((size_t)pl << 16) + (size_t)(y1 * 256 + x1)) * 32);
            for (int cq = 0; cq < 4; ++cq) {   // runtime loop: keeps code in I$
                ushort8v v00 = r00[cq], v01 = r01[cq], v10 = r10[cq], v11 = r11[cq];
                #pragma unroll
                for (int e = 0; e < 8; ++e) {
                    float f = bf2f(v00[e]) * w00 + bf2f(v01[e]) * w01
                            + bf2f(v10[e]) * w10 + bf2f(v11[e]) * w11;
                    const float* __restrict__ wr = w1 + (size_t)((pl * 32 + cq * 8 + e) * 64);
                    #pragma unroll
                    for (int j = 0; j < 64; ++j) h[j] = fmaf(f, wr[j], h[j]);  // wr uniform -> s_load
                }
            }
        } else {
            for (int c = 0; c < 32; ++c) {
                const float* b = splane + (size_t)c * 65536;
                float f = b[y0 * 256 + x0] * w00 + b[y0 * 256 + x1] * w01
                        + b[y1 * 256 + x0] * w10 + b[y1 * 256 + x1] * w11;
                const float* __restrict__ wr = w1 + (size_t)((pl * 32 + c) * 64);
                #pragma unroll
                for (int j = 0; j < 64; ++j) h[j] = fmaf(f, wr[j], h[j]);
            }
        }
    };
    samp(gx, gy, 0, pxy);
    samp(gx, gz, 1, pxz);
    samp(gy, gz, 2, pyz);

    // relu(h) -> stash (runtime-k access next; regs can't be runtime-indexed)
    #pragma unroll
    for (int j = 0; j < 64; ++j) act[j][tid] = f2bf(fmaxf(h[j], 0.0f));

    // Layer 2: out16 = h @ w2 (64x16)
    float o[16];
    #pragma unroll
    for (int j = 0; j < 16; ++j) o[j] = 0.0f;
    for (int k = 0; k < 64; ++k) {
        float hv = bf2f(act[k][tid]);
        const float* __restrict__ wr = w2 + (size_t)(k * 16);
        #pragma unroll
        for (int j = 0; j < 16; ++j) o[j] = fmaf(hv, wr[j], o[j]);
    }
    out[(size_t)3 * npts + i] = o[0];   // sigma (f32)

    // Layer 3: c1 = relu(out16[:,1:16] @ wc1 (15,64))
    float c1[64];
    #pragma unroll
    for (int j = 0; j < 64; ++j) c1[j] = 0.0f;
    #pragma unroll
    for (int k = 0; k < 15; ++k) {
        const float* __restrict__ wr = wc1 + (size_t)(k * 64);
        #pragma unroll
        for (int j = 0; j < 64; ++j) c1[j] = fmaf(o[k + 1], wr[j], c1[j]);
    }
    #pragma unroll
    for (int j = 0; j < 64; ++j) act[j][tid] = f2bf(fmaxf(c1[j], 0.0f));

    // Layer 4: c2 = c1 @ wc2 (64,64)
    float c2[64];
    #pragma unroll
    for (int j = 0; j < 64; ++j) c2[j] = 0.0f;
    for (int k = 0; k < 64; ++k) {
        float v = bf2f(act[k][tid]);
        const float* __restrict__ wr = wc2 + (size_t)(k * 64);
        #pragma unroll
        for (int j = 0; j < 64; ++j) c2[j] = fmaf(v, wr[j], c2[j]);
    }

    // Layer 5: color = sigmoid(relu(c2) @ wc3 (64,3))
    float r0 = 0.0f, r1 = 0.0f, r2 = 0.0f;
    #pragma unroll
    for (int k = 0; k < 64; ++k) {
        float v = fmaxf(c2[k], 0.0f);
        r0 = fmaf(v, wc3[k * 3 + 0], r0);
        r1 = fmaf(v, wc3[k * 3 + 1], r1);
        r2 = fmaf(v, wc3[k * 3 + 2], r2);
    }
    out[(size_t)3 * i + 0] = 1.0f / (1.0f + expf(-r0));
    out[(size_t)3 * i + 1] = 1.0f / (1.0f + expf(-r1));
    out[(size_t)3 * i + 2] = 1.0f / (1.0f + expf(-r2));
}

extern "C" void kernel_launch(void* const* d_in, const int* in_sizes, int n_in,
                              void* d_out, int out_size, void* d_ws, size_t ws_size,
                              hipStream_t stream) {
    const float* x      = (const float*)d_in[0];
    // d_in[1] = view dirs `d` — unused by the reference network
    const float* pxy    = (const float*)d_in[2];
    const float* pxz    = (const float*)d_in[3];
    const float* pyz    = (const float*)d_in[4];
    const float* center = (const float*)d_in[5];
    const float* scale  = (const float*)d_in[6];
    const float* w1     = (const float*)d_in[7];
    const float* w2     = (const float*)d_in[8];
    const float* wc1    = (const float*)d_in[9];
    const float* wc2    = (const float*)d_in[10];
    const float* wc3    = (const float*)d_in[11];
    float* out = (float*)d_out;   // reference outputs are float32
    const int npts = in_sizes[0] / 3;

    const size_t tp_bytes = (size_t)3 * 256 * 256 * 32 * 2;  // 12.6 MB bf16 transposed planes
    if (ws_size >= tp_bytes) {
        const int tot = 3 * 256 * 256 * 16;
        transpose_planes_kernel<<<(tot + 255) / 256, 256, 0, stream>>>(
            pxy, pxz, pyz, (unsigned int*)d_ws);
        nerf_fused_kernel<true><<<(npts + 255) / 256, 256, 0, stream>>>(
            x, pxy, pxz, pyz, (const unsigned short*)d_ws, center, scale,
            w1, w2, wc1, wc2, wc3, out, npts);
    } else {
        nerf_fused_kernel<false><<<(npts + 255) / 256, 256, 0, stream>>>(
            x, pxy, pxz, pyz, nullptr, center, scale,
            w1, w2, wc1, wc2, wc3, out, npts);
    }
}

// Round 4
// 232.925 us; speedup vs baseline: 1.8055x; 1.8055x over previous
//
#include <hip/hip_runtime.h>
#include <stdint.h>

typedef __attribute__((ext_vector_type(8))) unsigned short ushort8v;
typedef __attribute__((ext_vector_type(8))) short bf16x8;
typedef __attribute__((ext_vector_type(4))) float f32x4;
typedef __attribute__((ext_vector_type(4))) unsigned int uint4v;

__device__ __forceinline__ float bf2f(unsigned short u) {
    return __uint_as_float(((unsigned)u) << 16);
}
__device__ __forceinline__ unsigned short f2bf(float f) {
    unsigned u = __float_as_uint(f);
    unsigned r = u + 0x7fffu + ((u >> 16) & 1u);   // RNE
    return (unsigned short)(r >> 16);
}
__device__ __forceinline__ unsigned cvt_pk_bf16(float lo, float hi) {
    unsigned r;
    asm("v_cvt_pk_bf16_f32 %0, %1, %2" : "=v"(r) : "v"(lo), "v"(hi));
    return r;
}

// ---------------- pre-pass 1: planes (3 x [32][256][256] f32) -> [3][y][x][c] bf16
__global__ __launch_bounds__(256) void transpose_planes_kernel(
    const float* __restrict__ pxy, const float* __restrict__ pxz,
    const float* __restrict__ pyz, unsigned int* __restrict__ tp)
{
    int t = blockIdx.x * 256 + threadIdx.x;
    if (t >= 3 * 256 * 256 * 16) return;
    int cp  = t & 15;
    int tex = t >> 4;
    int pidx = tex >> 16;
    int yx  = tex & 65535;
    const float* src = (pidx == 0) ? pxy : ((pidx == 1) ? pxz : pyz);
    float f0 = src[(size_t)(2 * cp)     * 65536 + yx];
    float f1 = src[(size_t)(2 * cp + 1) * 65536 + yx];
    tp[t] = ((unsigned)f2bf(f1) << 16) | (unsigned)f2bf(f0);
}

// ---------------- pre-pass 2: pack all MLP weights (transposed) into MFMA A-frag layout
// A-matrices (all [Mout x K], A[of][k]):
//  L1: w1^T [64x96]   tiles 0..11  (kc*4+mt)
//  L2: w2^T [16x64]   tiles 12..13 (kc)
//  L3: wc1 padded [64x32], row k=0 zero, k=1..15 -> wc1[k-1][of]   tiles 14..17 (mt)
//  L4: wc2^T [64x64]  tiles 18..25 (kc*4+mt)
//  L5: wc3^T padded [16x64], of<3 else 0   tiles 26..27 (kc)
// Frag layout per tile (1 KB): lane l holds A[mt*16+(l&15)][kc*32+(l>>4)*8+j], j=0..7.
__global__ __launch_bounds__(256) void pack_weights_kernel(
    const float* __restrict__ w1, const float* __restrict__ w2,
    const float* __restrict__ wc1, const float* __restrict__ wc2,
    const float* __restrict__ wc3, unsigned int* __restrict__ pack)
{
    int t = blockIdx.x * 256 + threadIdx.x;
    if (t >= 28 * 64) return;
    int lane = t & 63, tile = t >> 6;
    int mat, mt, kc;
    if (tile < 12)      { mat = 0; kc = tile >> 2;        mt = tile & 3; }
    else if (tile < 14) { mat = 1; kc = tile - 12;        mt = 0; }
    else if (tile < 18) { mat = 2; kc = 0;                mt = tile - 14; }
    else if (tile < 26) { mat = 3; kc = (tile - 18) >> 2; mt = (tile - 18) & 3; }
    else                { mat = 4; kc = tile - 26;        mt = 0; }
    int of = mt * 16 + (lane & 15);
    int kb = kc * 32 + (lane >> 4) * 8;
    float f[8];
    #pragma unroll
    for (int j = 0; j < 8; ++j) {
        int k = kb + j;
        float v;
        if (mat == 0)      v = w1[k * 64 + of];
        else if (mat == 1) v = w2[k * 16 + of];
        else if (mat == 2) v = (k >= 1 && k < 16) ? wc1[(k - 1) * 64 + of] : 0.0f;
        else if (mat == 3) v = wc2[k * 64 + of];
        else               v = (of < 3) ? wc3[k * 3 + of] : 0.0f;
        f[j] = v;
    }
    unsigned int* dst = pack + tile * 256 + lane * 4;
    #pragma unroll
    for (int w = 0; w < 4; ++w)
        dst[w] = ((unsigned)f2bf(f[2 * w + 1]) << 16) | (unsigned)f2bf(f[2 * w]);
}

// ---------------- main: wave = 16 points; transposed MFMA MLP chain, B-frags in regs
__global__ __launch_bounds__(256) void nerf_mfma_kernel(
    const float* __restrict__ xin,
    const unsigned short* __restrict__ tp,
    const unsigned int* __restrict__ wpack,
    const float* __restrict__ center, const float* __restrict__ scale,
    float* __restrict__ out, int npts, int ntiles)
{
    __shared__ unsigned int wlds[28 * 256];
    const int tid = threadIdx.x;
    #pragma unroll 4
    for (int idx = tid; idx < 28 * 256; idx += 256) wlds[idx] = wpack[idx];
    __syncthreads();

    const int lane = tid & 63;
    const int wv   = tid >> 6;
    const int p    = lane & 15;           // point column within wave tile
    const int G    = lane >> 4;           // k-group
    const bool hi32 = (lane & 32) != 0;
    const bf16x8* Af = (const bf16x8*)wlds;

    const float ctr0 = center[0], ctr1 = center[1], ctr2 = center[2];
    const float sc0 = scale[0], sc1 = scale[1], sc2 = scale[2];

    for (int tile = blockIdx.x; tile < ntiles; tile += gridDim.x) {
        asm volatile("" ::: "memory");   // keep LDS frag reads inside the loop
        const int gpt = tile * 64 + wv * 16 + p;
        const bool valid = gpt < npts;
        const int rp = valid ? gpt : (npts - 1);
        const float xv = xin[3 * rp + 0], yv = xin[3 * rp + 1], zv = xin[3 * rp + 2];

        auto norm1 = [&](float v, float c, float s) {
            float xn = fminf(fmaxf((v - c) / s + 0.5f, 0.0f), 1.0f);
            return xn * 2.0f - 1.0f;
        };
        const float gx = norm1(xv, ctr0, sc0);
        const float gy = norm1(yv, ctr1, sc1);
        const float gz = norm1(zv, ctr2, sc2);
        const float us[3] = {gx, gx, gy};
        const float vs[3] = {gy, gz, gz};

        // ---- L1: h^T = relu(W1^T @ feat^T), gather feeds B-frags directly
        f32x4 acc1[4];
        #pragma unroll
        for (int mt = 0; mt < 4; ++mt) acc1[mt] = f32x4{0.f, 0.f, 0.f, 0.f};
        #pragma unroll
        for (int pl = 0; pl < 3; ++pl) {
            float pxf = (us[pl] + 1.0f) * 0.5f * 255.0f;
            float pyf = (vs[pl] + 1.0f) * 0.5f * 255.0f;
            float x0f = floorf(pxf), y0f = floorf(pyf);
            float wx = pxf - x0f, wy = pyf - y0f;
            int x0 = min(max((int)x0f, 0), 255), y0 = min(max((int)y0f, 0), 255);
            int x1 = min(x0 + 1, 255), y1 = min(y0 + 1, 255);
            float w00 = (1.f - wx) * (1.f - wy), w01 = wx * (1.f - wy);
            float w10 = (1.f - wx) * wy,         w11 = wx * wy;
            const size_t pbase = ((size_t)pl << 16);
            const ushort8v v00 = *(const ushort8v*)(tp + (pbase + (size_t)(y0 * 256 + x0)) * 32 + G * 8);
            const ushort8v v01 = *(const ushort8v*)(tp + (pbase + (size_t)(y0 * 256 + x1)) * 32 + G * 8);
            const ushort8v v10 = *(const ushort8v*)(tp + (pbase + (size_t)(y1 * 256 + x0)) * 32 + G * 8);
            const ushort8v v11 = *(const ushort8v*)(tp + (pbase + (size_t)(y1 * 256 + x1)) * 32 + G * 8);
            uint4v bw;
            #pragma unroll
            for (int w = 0; w < 4; ++w) {
                float f0 = bf2f(v00[2*w]) * w00 + bf2f(v01[2*w]) * w01
                         + bf2f(v10[2*w]) * w10 + bf2f(v11[2*w]) * w11;
                float f1 = bf2f(v00[2*w+1]) * w00 + bf2f(v01[2*w+1]) * w01
                         + bf2f(v10[2*w+1]) * w10 + bf2f(v11[2*w+1]) * w11;
                bw[w] = cvt_pk_bf16(f0, f1);
            }
            bf16x8 bfr = __builtin_bit_cast(bf16x8, bw);
            #pragma unroll
            for (int mt = 0; mt < 4; ++mt)
                acc1[mt] = __builtin_amdgcn_mfma_f32_16x16x32_bf16(
                    Af[(pl * 4 + mt) * 64 + lane], bfr, acc1[mt], 0, 0, 0);
        }

        // ---- repack h (relu) -> B-frags; L2: o^T = W2^T @ h^T
        unsigned pk1[4][2];
        #pragma unroll
        for (int mt = 0; mt < 4; ++mt) {
            pk1[mt][0] = cvt_pk_bf16(fmaxf(acc1[mt][0], 0.f), fmaxf(acc1[mt][1], 0.f));
            pk1[mt][1] = cvt_pk_bf16(fmaxf(acc1[mt][2], 0.f), fmaxf(acc1[mt][3], 0.f));
        }
        f32x4 acc2 = f32x4{0.f, 0.f, 0.f, 0.f};
        #pragma unroll
        for (int kc2 = 0; kc2 < 2; ++kc2) {
            uint4v bw;
            #pragma unroll
            for (int w = 0; w < 4; ++w) {
                int src = p + 16 * (2 * (G & 1) + (w >> 1));
                unsigned lo_ = (unsigned)__shfl((int)pk1[2 * kc2][w & 1], src, 64);
                unsigned hi_ = (unsigned)__shfl((int)pk1[2 * kc2 + 1][w & 1], src, 64);
                bw[w] = hi32 ? hi_ : lo_;
            }
            acc2 = __builtin_amdgcn_mfma_f32_16x16x32_bf16(
                Af[(12 + kc2) * 64 + lane], __builtin_bit_cast(bf16x8, bw), acc2, 0, 0, 0);
        }
        if (valid && lane < 16) out[(size_t)3 * npts + gpt] = acc2[0];   // sigma = o[0]

        // ---- repack o (no relu; k = of, zero row-0 weight kills sigma) -> b3; L3
        unsigned pk2[2];
        pk2[0] = cvt_pk_bf16(acc2[0], acc2[1]);
        pk2[1] = cvt_pk_bf16(acc2[2], acc2[3]);
        uint4v bw3;
        #pragma unroll
        for (int w = 0; w < 4; ++w) {
            int src = p + 16 * (2 * (G & 1) + (w >> 1));
            unsigned v = (unsigned)__shfl((int)pk2[w & 1], src, 64);
            bw3[w] = (G < 2) ? v : 0u;
        }
        bf16x8 b3 = __builtin_bit_cast(bf16x8, bw3);
        f32x4 acc3[4];
        #pragma unroll
        for (int mt = 0; mt < 4; ++mt) acc3[mt] = f32x4{0.f, 0.f, 0.f, 0.f};
        #pragma unroll
        for (int mt = 0; mt < 4; ++mt)
            acc3[mt] = __builtin_amdgcn_mfma_f32_16x16x32_bf16(
                Af[(14 + mt) * 64 + lane], b3, acc3[mt], 0, 0, 0);

        // ---- repack c1 (relu) -> b4; L4
        unsigned pk3[4][2];
        #pragma unroll
        for (int mt = 0; mt < 4; ++mt) {
            pk3[mt][0] = cvt_pk_bf16(fmaxf(acc3[mt][0], 0.f), fmaxf(acc3[mt][1], 0.f));
            pk3[mt][1] = cvt_pk_bf16(fmaxf(acc3[mt][2], 0.f), fmaxf(acc3[mt][3], 0.f));
        }
        f32x4 acc4[4];
        #pragma unroll
        for (int mt = 0; mt < 4; ++mt) acc4[mt] = f32x4{0.f, 0.f, 0.f, 0.f};
        #pragma unroll
        for (int kc2 = 0; kc2 < 2; ++kc2) {
            uint4v bw;
            #pragma unroll
            for (int w = 0; w < 4; ++w) {
                int src = p + 16 * (2 * (G & 1) + (w >> 1));
                unsigned lo_ = (unsigned)__shfl((int)pk3[2 * kc2][w & 1], src, 64);
                unsigned hi_ = (unsigned)__shfl((int)pk3[2 * kc2 + 1][w & 1], src, 64);
                bw[w] = hi32 ? hi_ : lo_;
            }
            bf16x8 b = __builtin_bit_cast(bf16x8, bw);
            #pragma unroll
            for (int mt = 0; mt < 4; ++mt)
                acc4[mt] = __builtin_amdgcn_mfma_f32_16x16x32_bf16(
                    Af[(18 + kc2 * 4 + mt) * 64 + lane], b, acc4[mt], 0, 0, 0);
        }

        // ---- repack c2 (relu) -> b5; L5: color^T = Wc3^T @ relu(c2)^T
        unsigned pk4[4][2];
        #pragma unroll
        for (int mt = 0; mt < 4; ++mt) {
            pk4[mt][0] = cvt_pk_bf16(fmaxf(acc4[mt][0], 0.f), fmaxf(acc4[mt][1], 0.f));
            pk4[mt][1] = cvt_pk_bf16(fmaxf(acc4[mt][2], 0.f), fmaxf(acc4[mt][3], 0.f));
        }
        f32x4 acc5 = f32x4{0.f, 0.f, 0.f, 0.f};
        #pragma unroll
        for (int kc2 = 0; kc2 < 2; ++kc2) {
            uint4v bw;
            #pragma unroll
            for (int w = 0; w < 4; ++w) {
                int src = p + 16 * (2 * (G & 1) + (w >> 1));
                unsigned lo_ = (unsigned)__shfl((int)pk4[2 * kc2][w & 1], src, 64);
                unsigned hi_ = (unsigned)__shfl((int)pk4[2 * kc2 + 1][w & 1], src, 64);
                bw[w] = hi32 ? hi_ : lo_;
            }
            acc5 = __builtin_amdgcn_mfma_f32_16x16x32_bf16(
                Af[(26 + kc2) * 64 + lane], __builtin_bit_cast(bf16x8, bw), acc5, 0, 0, 0);
        }
        if (valid && lane < 16) {
            out[(size_t)3 * gpt + 0] = 1.0f / (1.0f + __expf(-acc5[0]));
            out[(size_t)3 * gpt + 1] = 1.0f / (1.0f + __expf(-acc5[1]));
            out[(size_t)3 * gpt + 2] = 1.0f / (1.0f + __expf(-acc5[2]));
        }
    }
}

// ---------------- fallback (ws too small): round-3 style pure-VALU kernel, f32 planes
__global__ __launch_bounds__(256) void nerf_fallback_kernel(
    const float* __restrict__ xin,
    const float* __restrict__ pxy, const float* __restrict__ pxz,
    const float* __restrict__ pyz,
    const float* __restrict__ center, const float* __restrict__ scale,
    const float* __restrict__ w1, const float* __restrict__ w2,
    const float* __restrict__ wc1, const float* __restrict__ wc2,
    const float* __restrict__ wc3, float* __restrict__ out, int npts)
{
    __shared__ unsigned short act[64][256];
    const int tid = threadIdx.x;
    const int i = blockIdx.x * 256 + tid;
    if (i >= npts) return;
    const float xv = xin[3 * i], yv = xin[3 * i + 1], zv = xin[3 * i + 2];
    auto norm1 = [&](float v, int k) {
        float xn = fminf(fmaxf((v - center[k]) / scale[k] + 0.5f, 0.0f), 1.0f);
        return xn * 2.0f - 1.0f;
    };
    const float gx = norm1(xv, 0), gy = norm1(yv, 1), gz = norm1(zv, 2);
    float h[64];
    #pragma unroll
    for (int j = 0; j < 64; ++j) h[j] = 0.0f;
    auto samp = [&](float gu, float gv, int pl, const float* __restrict__ splane) {
        float pxf = (gu + 1.0f) * 0.5f * 255.0f, pyf = (gv + 1.0f) * 0.5f * 255.0f;
        float x0f = floorf(pxf), y0f = floorf(pyf);
        float wx = pxf - x0f, wy = pyf - y0f;
        int x0 = min(max((int)x0f, 0), 255), y0 = min(max((int)y0f, 0), 255);
        int x1 = min(x0 + 1, 255), y1 = min(y0 + 1, 255);
        float w00 = (1 - wx) * (1 - wy), w01 = wx * (1 - wy), w10 = (1 - wx) * wy, w11 = wx * wy;
        for (int c = 0; c < 32; ++c) {
            const float* b = splane + (size_t)c * 65536;
            float f = b[y0 * 256 + x0] * w00 + b[y0 * 256 + x1] * w01
                    + b[y1 * 256 + x0] * w10 + b[y1 * 256 + x1] * w11;
            const float* wr = w1 + (size_t)((pl * 32 + c) * 64);
            #pragma unroll
            for (int j = 0; j < 64; ++j) h[j] = fmaf(f, wr[j], h[j]);
        }
    };
    samp(gx, gy, 0, pxy); samp(gx, gz, 1, pxz); samp(gy, gz, 2, pyz);
    #pragma unroll
    for (int j = 0; j < 64; ++j) act[j][tid] = f2bf(fmaxf(h[j], 0.0f));
    float o[16];
    #pragma unroll
    for (int j = 0; j < 16; ++j) o[j] = 0.0f;
    for (int k = 0; k < 64; ++k) {
        float hv = bf2f(act[k][tid]);
        #pragma unroll
        for (int j = 0; j < 16; ++j) o[j] = fmaf(hv, w2[k * 16 + j], o[j]);
    }
    out[(size_t)3 * npts + i] = o[0];
    float c1[64];
    #pragma unroll
    for (int j = 0; j < 64; ++j) c1[j] = 0.0f;
    #pragma unroll
    for (int k = 0; k < 15; ++k)
        #pragma unroll
        for (int j = 0; j < 64; ++j) c1[j] = fmaf(o[k + 1], wc1[k * 64 + j], c1[j]);
    #pragma unroll
    for (int j = 0; j < 64; ++j) act[j][tid] = f2bf(fmaxf(c1[j], 0.0f));
    float c2[64];
    #pragma unroll
    for (int j = 0; j < 64; ++j) c2[j] = 0.0f;
    for (int k = 0; k < 64; ++k) {
        float v = bf2f(act[k][tid]);
        #pragma unroll
        for (int j = 0; j < 64; ++j) c2[j] = fmaf(v, wc2[k * 64 + j], c2[j]);
    }
    float r0 = 0, r1 = 0, r2 = 0;
    #pragma unroll
    for (int k = 0; k < 64; ++k) {
        float v = fmaxf(c2[k], 0.0f);
        r0 = fmaf(v, wc3[k * 3 + 0], r0);
        r1 = fmaf(v, wc3[k * 3 + 1], r1);
        r2 = fmaf(v, wc3[k * 3 + 2], r2);
    }
    out[(size_t)3 * i + 0] = 1.0f / (1.0f + expf(-r0));
    out[(size_t)3 * i + 1] = 1.0f / (1.0f + expf(-r1));
    out[(size_t)3 * i + 2] = 1.0f / (1.0f + expf(-r2));
}

extern "C" void kernel_launch(void* const* d_in, const int* in_sizes, int n_in,
                              void* d_out, int out_size, void* d_ws, size_t ws_size,
                              hipStream_t stream) {
    const float* x      = (const float*)d_in[0];
    const float* pxy    = (const float*)d_in[2];
    const float* pxz    = (const float*)d_in[3];
    const float* pyz    = (const float*)d_in[4];
    const float* center = (const float*)d_in[5];
    const float* scale  = (const float*)d_in[6];
    const float* w1     = (const float*)d_in[7];
    const float* w2     = (const float*)d_in[8];
    const float* wc1    = (const float*)d_in[9];
    const float* wc2    = (const float*)d_in[10];
    const float* wc3    = (const float*)d_in[11];
    float* out = (float*)d_out;
    const int npts = in_sizes[0] / 3;

    const size_t tp_bytes = (size_t)3 * 256 * 256 * 32 * 2;   // 12.58 MB planes
    const size_t pack_bytes = 28 * 1024;                      // 28 KB weight frags
    if (ws_size >= tp_bytes + pack_bytes) {
        unsigned int* tp_ws   = (unsigned int*)d_ws;
        unsigned int* pack_ws = (unsigned int*)((char*)d_ws + tp_bytes);
        const int tot = 3 * 256 * 256 * 16;
        transpose_planes_kernel<<<(tot + 255) / 256, 256, 0, stream>>>(pxy, pxz, pyz, tp_ws);
        pack_weights_kernel<<<7, 256, 0, stream>>>(w1, w2, wc1, wc2, wc3, pack_ws);
        const int ntiles = (npts + 63) / 64;
        nerf_mfma_kernel<<<ntiles, 256, 0, stream>>>(
            x, (const unsigned short*)tp_ws, pack_ws, center, scale, out, npts, ntiles);
    } else {
        nerf_fallback_kernel<<<(npts + 255) / 256, 256, 0, stream>>>(
            x, pxy, pxz, pyz, center, scale, w1, w2, wc1, wc2, wc3, out, npts);
    }
}

// Round 5
// 187.633 us; speedup vs baseline: 2.2414x; 1.2414x over previous
//
#include <hip/hip_runtime.h>
#include <stdint.h>

typedef __attribute__((ext_vector_type(8))) unsigned short ushort8v;
typedef __attribute__((ext_vector_type(8))) short bf16x8;
typedef __attribute__((ext_vector_type(4))) float f32x4;
typedef __attribute__((ext_vector_type(2))) float f32x2;
typedef __attribute__((ext_vector_type(4))) unsigned int uint4v;

__device__ __forceinline__ float bf2f(unsigned short u) {
    return __uint_as_float(((unsigned)u) << 16);
}
__device__ __forceinline__ unsigned short f2bf(float f) {
    unsigned u = __float_as_uint(f);
    unsigned r = u + 0x7fffu + ((u >> 16) & 1u);   // RNE
    return (unsigned short)(r >> 16);
}
__device__ __forceinline__ unsigned cvt_pk_bf16(float lo, float hi) {
    unsigned r;
    asm("v_cvt_pk_bf16_f32 %0, %1, %2" : "=v"(r) : "v"(lo), "v"(hi));
    return r;
}
// unpack a bf16-pair word to two f32 (lo = <<16, hi = mask) — 2 VALU ops
__device__ __forceinline__ f32x2 up2(unsigned u) {
    f32x2 r;
    r[0] = __uint_as_float(u << 16);
    r[1] = __uint_as_float(u & 0xffff0000u);
    return r;
}

// ---------------- pre-pass 1: planes (3 x [32][256][256] f32) -> [3][y][x][c] bf16
// LDS-tiled: coalesced float4 reads per channel row, pad-17 LDS, dwordx4 writes.
__global__ __launch_bounds__(256) void transpose_planes_kernel(
    const float* __restrict__ pxy, const float* __restrict__ pxz,
    const float* __restrict__ pyz, unsigned int* __restrict__ tp)
{
    __shared__ unsigned int lt[64 * 17];   // [yx][c2], pad 17 kills bank conflicts
    const int bid = blockIdx.x;
    const int plane = bid >> 10;           // 1024 blocks per plane
    const int base = (bid & 1023) * 64;    // 64 pixels per block
    const float* __restrict__ src = plane == 0 ? pxy : (plane == 1 ? pxz : pyz);
    const int tid = threadIdx.x;
    {
        const int c2 = tid >> 4;           // channel pair 0..15
        const int s  = tid & 15;           // pixel group (4 px)
        const f32x4 va = *(const f32x4*)(src + (size_t)(2 * c2)     * 65536 + base + 4 * s);
        const f32x4 vb = *(const f32x4*)(src + (size_t)(2 * c2 + 1) * 65536 + base + 4 * s);
        #pragma unroll
        for (int j = 0; j < 4; ++j) {
            int yx = 4 * s + j;
            lt[yx * 17 + c2] = ((unsigned)f2bf(vb[j]) << 16) | (unsigned)f2bf(va[j]);
        }
    }
    __syncthreads();
    {
        const int yx = tid >> 2, q = tid & 3;
        uint4v o;
        #pragma unroll
        for (int k = 0; k < 4; ++k) o[k] = lt[yx * 17 + 4 * q + k];
        *(uint4v*)(tp + ((size_t)plane * 65536 + base + yx) * 16 + 4 * q) = o;
    }
}

// ---------------- pre-pass 2: pack MLP weights (transposed) into swizzled MFMA A-frag layout
// Frag layout per tile (1 KB): lane l's 16B at slot (l ^ (l>>3)) — conflict-free b128 reads.
// lane l holds A[mt*16+(l&15)][kc*32+(l>>4)*8+j], j=0..7.
__global__ __launch_bounds__(256) void pack_weights_kernel(
    const float* __restrict__ w1, const float* __restrict__ w2,
    const float* __restrict__ wc1, const float* __restrict__ wc2,
    const float* __restrict__ wc3, unsigned int* __restrict__ pack)
{
    int t = blockIdx.x * 256 + threadIdx.x;
    if (t >= 28 * 64) return;
    int lane = t & 63, tile = t >> 6;
    int mat, mt, kc;
    if (tile < 12)      { mat = 0; kc = tile >> 2;        mt = tile & 3; }
    else if (tile < 14) { mat = 1; kc = tile - 12;        mt = 0; }
    else if (tile < 18) { mat = 2; kc = 0;                mt = tile - 14; }
    else if (tile < 26) { mat = 3; kc = (tile - 18) >> 2; mt = (tile - 18) & 3; }
    else                { mat = 4; kc = tile - 26;        mt = 0; }
    int of = mt * 16 + (lane & 15);
    int kb = kc * 32 + (lane >> 4) * 8;
    float f[8];
    #pragma unroll
    for (int j = 0; j < 8; ++j) {
        int k = kb + j;
        float v;
        if (mat == 0)      v = w1[k * 64 + of];
        else if (mat == 1) v = w2[k * 16 + of];
        else if (mat == 2) v = (k >= 1 && k < 16) ? wc1[(k - 1) * 64 + of] : 0.0f;
        else if (mat == 3) v = wc2[k * 64 + of];
        else               v = (of < 3) ? wc3[k * 3 + of] : 0.0f;
        f[j] = v;
    }
    int sl = lane ^ (lane >> 3);                   // XOR swizzle (bank-conflict-free)
    unsigned int* dst = pack + tile * 256 + sl * 4;
    #pragma unroll
    for (int w = 0; w < 4; ++w)
        dst[w] = ((unsigned)f2bf(f[2 * w + 1]) << 16) | (unsigned)f2bf(f[2 * w]);
}

// ---------------- main: wave = 16 points; transposed MFMA MLP chain, B-frags in regs
// 512 threads (8 waves), grid-stride: weight preload amortized over 16 wavetiles/block-iter.
__global__ __launch_bounds__(512) void nerf_mfma_kernel(
    const float* __restrict__ xin,
    const unsigned short* __restrict__ tp,
    const unsigned int* __restrict__ wpack,
    const float* __restrict__ center, const float* __restrict__ scale,
    float* __restrict__ out, int npts, int nwt)
{
    __shared__ unsigned int wlds[28 * 256];
    const int tid = threadIdx.x;
    #pragma unroll 2
    for (int idx = tid; idx < 28 * 256; idx += 512) wlds[idx] = wpack[idx];
    __syncthreads();

    const int lane = tid & 63;
    const int wv   = tid >> 6;            // 0..7
    const int p    = lane & 15;           // point column within wave tile
    const int G    = lane >> 4;           // k-group
    const bool hi32 = (lane & 32) != 0;
    const int sl   = lane ^ (lane >> 3);  // swizzled frag slot
    const bf16x8* Af = (const bf16x8*)wlds;

    const float ctr0 = center[0], ctr1 = center[1], ctr2 = center[2];
    const float sc0 = scale[0], sc1 = scale[1], sc2 = scale[2];

    for (int wtb = blockIdx.x * 8; wtb < nwt; wtb += gridDim.x * 8) {
        asm volatile("" ::: "memory");   // keep LDS frag reads inside the loop
        const int wt = wtb + wv;
        const int gpt = wt * 16 + p;
        const bool valid = (wt < nwt) && (gpt < npts);
        const int rp = valid ? gpt : (npts - 1);
        const float xv = xin[3 * rp + 0], yv = xin[3 * rp + 1], zv = xin[3 * rp + 2];

        auto norm1 = [&](float v, float c, float s) {
            float xn = fminf(fmaxf((v - c) / s + 0.5f, 0.0f), 1.0f);
            return xn * 2.0f - 1.0f;
        };
        const float gx = norm1(xv, ctr0, sc0);
        const float gy = norm1(yv, ctr1, sc1);
        const float gz = norm1(zv, ctr2, sc2);
        const float us[3] = {gx, gx, gy};
        const float vs[3] = {gy, gz, gz};

        // ---- L1: h^T = relu(W1^T @ feat^T), gather feeds B-frags directly
        f32x4 acc1[4];
        #pragma unroll
        for (int mt = 0; mt < 4; ++mt) acc1[mt] = f32x4{0.f, 0.f, 0.f, 0.f};
        #pragma unroll
        for (int pl = 0; pl < 3; ++pl) {
            float pxf = (us[pl] + 1.0f) * 0.5f * 255.0f;
            float pyf = (vs[pl] + 1.0f) * 0.5f * 255.0f;
            float x0f = floorf(pxf), y0f = floorf(pyf);
            float wx = pxf - x0f, wy = pyf - y0f;
            int x0 = min(max((int)x0f, 0), 255), y0 = min(max((int)y0f, 0), 255);
            int x1 = min(x0 + 1, 255), y1 = min(y0 + 1, 255);
            float w00 = (1.f - wx) * (1.f - wy), w01 = wx * (1.f - wy);
            float w10 = (1.f - wx) * wy,         w11 = wx * wy;
            const f32x2 W00 = {w00, w00}, W01 = {w01, w01}, W10 = {w10, w10}, W11 = {w11, w11};
            const size_t pbase = ((size_t)pl << 16);
            const uint4v v00 = *(const uint4v*)(tp + (pbase + (size_t)(y0 * 256 + x0)) * 32 + G * 8);
            const uint4v v01 = *(const uint4v*)(tp + (pbase + (size_t)(y0 * 256 + x1)) * 32 + G * 8);
            const uint4v v10 = *(const uint4v*)(tp + (pbase + (size_t)(y1 * 256 + x0)) * 32 + G * 8);
            const uint4v v11 = *(const uint4v*)(tp + (pbase + (size_t)(y1 * 256 + x1)) * 32 + G * 8);
            uint4v bw;
            #pragma unroll
            for (int w = 0; w < 4; ++w) {
                f32x2 a = up2(v00[w]) * W00 + up2(v01[w]) * W01
                        + up2(v10[w]) * W10 + up2(v11[w]) * W11;   // v_pk_fma_f32
                bw[w] = cvt_pk_bf16(a[0], a[1]);
            }
            bf16x8 bfr = __builtin_bit_cast(bf16x8, bw);
            #pragma unroll
            for (int mt = 0; mt < 4; ++mt)
                acc1[mt] = __builtin_amdgcn_mfma_f32_16x16x32_bf16(
                    Af[(pl * 4 + mt) * 64 + sl], bfr, acc1[mt], 0, 0, 0);
        }

        // ---- repack h (relu) -> B-frags; L2: o^T = W2^T @ h^T
        unsigned pk1[4][2];
        #pragma unroll
        for (int mt = 0; mt < 4; ++mt) {
            pk1[mt][0] = cvt_pk_bf16(fmaxf(acc1[mt][0], 0.f), fmaxf(acc1[mt][1], 0.f));
            pk1[mt][1] = cvt_pk_bf16(fmaxf(acc1[mt][2], 0.f), fmaxf(acc1[mt][3], 0.f));
        }
        f32x4 acc2 = f32x4{0.f, 0.f, 0.f, 0.f};
        #pragma unroll
        for (int kc2 = 0; kc2 < 2; ++kc2) {
            uint4v bw;
            #pragma unroll
            for (int w = 0; w < 4; ++w) {
                int src = p + 16 * (2 * (G & 1) + (w >> 1));
                unsigned lo_ = (unsigned)__shfl((int)pk1[2 * kc2][w & 1], src, 64);
                unsigned hi_ = (unsigned)__shfl((int)pk1[2 * kc2 + 1][w & 1], src, 64);
                bw[w] = hi32 ? hi_ : lo_;
            }
            acc2 = __builtin_amdgcn_mfma_f32_16x16x32_bf16(
                Af[(12 + kc2) * 64 + sl], __builtin_bit_cast(bf16x8, bw), acc2, 0, 0, 0);
        }
        if (valid && lane < 16) out[(size_t)3 * npts + gpt] = acc2[0];   // sigma = o[0]

        // ---- repack o (no relu; k = of, zero row-0 weight kills sigma) -> b3; L3
        unsigned pk2[2];
        pk2[0] = cvt_pk_bf16(acc2[0], acc2[1]);
        pk2[1] = cvt_pk_bf16(acc2[2], acc2[3]);
        uint4v bw3;
        #pragma unroll
        for (int w = 0; w < 4; ++w) {
            int src = p + 16 * (2 * (G & 1) + (w >> 1));
            unsigned v = (unsigned)__shfl((int)pk2[w & 1], src, 64);
            bw3[w] = (G < 2) ? v : 0u;
        }
        bf16x8 b3 = __builtin_bit_cast(bf16x8, bw3);
        f32x4 acc3[4];
        #pragma unroll
        for (int mt = 0; mt < 4; ++mt) acc3[mt] = f32x4{0.f, 0.f, 0.f, 0.f};
        #pragma unroll
        for (int mt = 0; mt < 4; ++mt)
            acc3[mt] = __builtin_amdgcn_mfma_f32_16x16x32_bf16(
                Af[(14 + mt) * 64 + sl], b3, acc3[mt], 0, 0, 0);

        // ---- repack c1 (relu) -> b4; L4
        unsigned pk3[4][2];
        #pragma unroll
        for (int mt = 0; mt < 4; ++mt) {
            pk3[mt][0] = cvt_pk_bf16(fmaxf(acc3[mt][0], 0.f), fmaxf(acc3[mt][1], 0.f));
            pk3[mt][1] = cvt_pk_bf16(fmaxf(acc3[mt][2], 0.f), fmaxf(acc3[mt][3], 0.f));
        }
        f32x4 acc4[4];
        #pragma unroll
        for (int mt = 0; mt < 4; ++mt) acc4[mt] = f32x4{0.f, 0.f, 0.f, 0.f};
        #pragma unroll
        for (int kc2 = 0; kc2 < 2; ++kc2) {
            uint4v bw;
            #pragma unroll
            for (int w = 0; w < 4; ++w) {
                int src = p + 16 * (2 * (G & 1) + (w >> 1));
                unsigned lo_ = (unsigned)__shfl((int)pk3[2 * kc2][w & 1], src, 64);
                unsigned hi_ = (unsigned)__shfl((int)pk3[2 * kc2 + 1][w & 1], src, 64);
                bw[w] = hi32 ? hi_ : lo_;
            }
            bf16x8 b = __builtin_bit_cast(bf16x8, bw);
            #pragma unroll
            for (int mt = 0; mt < 4; ++mt)
                acc4[mt] = __builtin_amdgcn_mfma_f32_16x16x32_bf16(
                    Af[(18 + kc2 * 4 + mt) * 64 + sl], b, acc4[mt], 0, 0, 0);
        }

        // ---- repack c2 (relu) -> b5; L5: color^T = Wc3^T @ relu(c2)^T
        unsigned pk4[4][2];
        #pragma unroll
        for (int mt = 0; mt < 4; ++mt) {
            pk4[mt][0] = cvt_pk_bf16(fmaxf(acc4[mt][0], 0.f), fmaxf(acc4[mt][1], 0.f));
            pk4[mt][1] = cvt_pk_bf16(fmaxf(acc4[mt][2], 0.f), fmaxf(acc4[mt][3], 0.f));
        }
        f32x4 acc5 = f32x4{0.f, 0.f, 0.f, 0.f};
        #pragma unroll
        for (int kc2 = 0; kc2 < 2; ++kc2) {
            uint4v bw;
            #pragma unroll
            for (int w = 0; w < 4; ++w) {
                int src = p + 16 * (2 * (G & 1) + (w >> 1));
                unsigned lo_ = (unsigned)__shfl((int)pk4[2 * kc2][w & 1], src, 64);
                unsigned hi_ = (unsigned)__shfl((int)pk4[2 * kc2 + 1][w & 1], src, 64);
                bw[w] = hi32 ? hi_ : lo_;
            }
            acc5 = __builtin_amdgcn_mfma_f32_16x16x32_bf16(
                Af[(26 + kc2) * 64 + sl], __builtin_bit_cast(bf16x8, bw), acc5, 0, 0, 0);
        }
        if (valid && lane < 16) {
            out[(size_t)3 * gpt + 0] = 1.0f / (1.0f + __expf(-acc5[0]));
            out[(size_t)3 * gpt + 1] = 1.0f / (1.0f + __expf(-acc5[1]));
            out[(size_t)3 * gpt + 2] = 1.0f / (1.0f + __expf(-acc5[2]));
        }
    }
}

// ---------------- fallback (ws too small): round-3 style pure-VALU kernel, f32 planes
__global__ __launch_bounds__(256) void nerf_fallback_kernel(
    const float* __restrict__ xin,
    const float* __restrict__ pxy, const float* __restrict__ pxz,
    const float* __restrict__ pyz,
    const float* __restrict__ center, const float* __restrict__ scale,
    const float* __restrict__ w1, const float* __restrict__ w2,
    const float* __restrict__ wc1, const float* __restrict__ wc2,
    const float* __restrict__ wc3, float* __restrict__ out, int npts)
{
    __shared__ unsigned short act[64][256];
    const int tid = threadIdx.x;
    const int i = blockIdx.x * 256 + tid;
    if (i >= npts) return;
    const float xv = xin[3 * i], yv = xin[3 * i + 1], zv = xin[3 * i + 2];
    auto norm1 = [&](float v, int k) {
        float xn = fminf(fmaxf((v - center[k]) / scale[k] + 0.5f, 0.0f), 1.0f);
        return xn * 2.0f - 1.0f;
    };
    const float gx = norm1(xv, 0), gy = norm1(yv, 1), gz = norm1(zv, 2);
    float h[64];
    #pragma unroll
    for (int j = 0; j < 64; ++j) h[j] = 0.0f;
    auto samp = [&](float gu, float gv, int pl, const float* __restrict__ splane) {
        float pxf = (gu + 1.0f) * 0.5f * 255.0f, pyf = (gv + 1.0f) * 0.5f * 255.0f;
        float x0f = floorf(pxf), y0f = floorf(pyf);
        float wx = pxf - x0f, wy = pyf - y0f;
        int x0 = min(max((int)x0f, 0), 255), y0 = min(max((int)y0f, 0), 255);
        int x1 = min(x0 + 1, 255), y1 = min(y0 + 1, 255);
        float w00 = (1 - wx) * (1 - wy), w01 = wx * (1 - wy), w10 = (1 - wx) * wy, w11 = wx * wy;
        for (int c = 0; c < 32; ++c) {
            const float* b = splane + (size_t)c * 65536;
            float f = b[y0 * 256 + x0] * w00 + b[y0 * 256 + x1] * w01
                    + b[y1 * 256 + x0] * w10 + b[y1 * 256 + x1] * w11;
            const float* wr = w1 + (size_t)((pl * 32 + c) * 64);
            #pragma unroll
            for (int j = 0; j < 64; ++j) h[j] = fmaf(f, wr[j], h[j]);
        }
    };
    samp(gx, gy, 0, pxy); samp(gx, gz, 1, pxz); samp(gy, gz, 2, pyz);
    #pragma unroll
    for (int j = 0; j < 64; ++j) act[j][tid] = f2bf(fmaxf(h[j], 0.0f));
    float o[16];
    #pragma unroll
    for (int j = 0; j < 16; ++j) o[j] = 0.0f;
    for (int k = 0; k < 64; ++k) {
        float hv = bf2f(act[k][tid]);
        #pragma unroll
        for (int j = 0; j < 16; ++j) o[j] = fmaf(hv, w2[k * 16 + j], o[j]);
    }
    out[(size_t)3 * npts + i] = o[0];
    float c1[64];
    #pragma unroll
    for (int j = 0; j < 64; ++j) c1[j] = 0.0f;
    #pragma unroll
    for (int k = 0; k < 15; ++k)
        #pragma unroll
        for (int j = 0; j < 64; ++j) c1[j] = fmaf(o[k + 1], wc1[k * 64 + j], c1[j]);
    #pragma unroll
    for (int j = 0; j < 64; ++j) act[j][tid] = f2bf(fmaxf(c1[j], 0.0f));
    float c2[64];
    #pragma unroll
    for (int j = 0; j < 64; ++j) c2[j] = 0.0f;
    for (int k = 0; k < 64; ++k) {
        float v = bf2f(act[k][tid]);
        #pragma unroll
        for (int j = 0; j < 64; ++j) c2[j] = fmaf(v, wc2[k * 64 + j], c2[j]);
    }
    float r0 = 0, r1 = 0, r2 = 0;
    #pragma unroll
    for (int k = 0; k < 64; ++k) {
        float v = fmaxf(c2[k], 0.0f);
        r0 = fmaf(v, wc3[k * 3 + 0], r0);
        r1 = fmaf(v, wc3[k * 3 + 1], r1);
        r2 = fmaf(v, wc3[k * 3 + 2], r2);
    }
    out[(size_t)3 * i + 0] = 1.0f / (1.0f + expf(-r0));
    out[(size_t)3 * i + 1] = 1.0f / (1.0f + expf(-r1));
    out[(size_t)3 * i + 2] = 1.0f / (1.0f + expf(-r2));
}

extern "C" void kernel_launch(void* const* d_in, const int* in_sizes, int n_in,
                              void* d_out, int out_size, void* d_ws, size_t ws_size,
                              hipStream_t stream) {
    const float* x      = (const float*)d_in[0];
    const float* pxy    = (const float*)d_in[2];
    const float* pxz    = (const float*)d_in[3];
    const float* pyz    = (const float*)d_in[4];
    const float* center = (const float*)d_in[5];
    const float* scale  = (const float*)d_in[6];
    const float* w1     = (const float*)d_in[7];
    const float* w2     = (const float*)d_in[8];
    const float* wc1    = (const float*)d_in[9];
    const float* wc2    = (const float*)d_in[10];
    const float* wc3    = (const float*)d_in[11];
    float* out = (float*)d_out;
    const int npts = in_sizes[0] / 3;

    const size_t tp_bytes = (size_t)3 * 256 * 256 * 32 * 2;   // 12.58 MB planes
    const size_t pack_bytes = 28 * 1024;                      // 28 KB weight frags
    if (ws_size >= tp_bytes + pack_bytes) {
        unsigned int* tp_ws   = (unsigned int*)d_ws;
        unsigned int* pack_ws = (unsigned int*)((char*)d_ws + tp_bytes);
        transpose_planes_kernel<<<3072, 256, 0, stream>>>(pxy, pxz, pyz, tp_ws);
        pack_weights_kernel<<<7, 256, 0, stream>>>(w1, w2, wc1, wc2, wc3, pack_ws);
        const int nwt = (npts + 15) / 16;
        nerf_mfma_kernel<<<1024, 512, 0, stream>>>(
            x, (const unsigned short*)tp_ws, pack_ws, center, scale, out, npts, nwt);
    } else {
        nerf_fallback_kernel<<<(npts + 255) / 256, 256, 0, stream>>>(
            x, pxy, pxz, pyz, center, scale, w1, w2, wc1, wc2, wc3, out, npts);
    }
}